// Round 1
// baseline (79.090 us; speedup 1.0000x reference)
//
#include <hip/hip_runtime.h>

#define NB 8
#define NP 131072
#define NM 16
#define NC 2
#define THRESH 0.5f
#define BLK 256
#define BLOCKS_PER_B (NP / BLK)          // 512
#define NBLOCKS (NB * BLOCKS_PER_B)      // 4096

// ---------- shared math helpers (must match reference op order) ----------

__device__ __forceinline__ float log_sigmoid(float x) {
    // jax.nn.log_sigmoid: -log1p(exp(-x)), computed stably
    return (x >= 0.0f) ? -log1pf(expf(-x)) : (x - log1pf(expf(x)));
}

__device__ __forceinline__ float focal_term(float x, bool pos) {
    float p = 1.0f / (1.0f + expf(-x));          // sigmoid
    float ce, omp;                                // ce, (1 - pt)
    if (pos) { ce = -log_sigmoid(x);  omp = 1.0f - p; }
    else     { ce = -log_sigmoid(-x); omp = p; }
    float w = pos ? 0.25f : 0.75f;                // ALPHA_W t + (1-ALPHA_W)(1-t)
    return w * omp * omp * ce;                    // GAMMA = 2
}

__device__ __forceinline__ float iou3d(const float blo[3], const float bhi[3], float va,
                                       const float plo[3], const float phi[3], float vb) {
    float inter = 1.0f;
#pragma unroll
    for (int k = 0; k < 3; ++k) {
        float lo = fmaxf(blo[k], plo[k]);
        float hi = fminf(bhi[k], phi[k]);
        inter *= fmaxf(hi - lo, 0.0f);
    }
    return inter / (va + vb - inter);
}

// L1 of |pred - encode(box, prior)| over 6 coords
__device__ __forceinline__ float l1_enc(const float* lp,
                                        const float blo[3], const float bhi[3],
                                        const float pc[3], const float ps[3]) {
    float s = 0.0f;
#pragma unroll
    for (int k = 0; k < 3; ++k) {
        float gc = (blo[k] + bhi[k]) * 0.5f;      // (lo+hi)/2
        float gs = bhi[k] - blo[k];
        float e  = (gc - pc[k]) / (ps[k] / 10.0f);
        float e2 = logf(gs / ps[k]) * 5.0f;
        s += fabsf(lp[k]     - e);
        s += fabsf(lp[3 + k] - e2);
    }
    return s;
}

// ---------- kernel A: match + pre-override loss partials ----------

__global__ __launch_bounds__(BLK) void match_loss_kernel(
        const float* __restrict__ locs, const float* __restrict__ scores,
        const float* __restrict__ boxes, const int* __restrict__ labels,
        const float* __restrict__ priors,
        unsigned long long* __restrict__ keys,        // [NB*NM], pre-zeroed
        float* __restrict__ focal_part, float* __restrict__ loc_part,
        int* __restrict__ npos_part) {
    __shared__ float s_blo[NM][3], s_bhi[NM][3], s_va[NM];
    __shared__ int   s_lab[NM];
    __shared__ unsigned long long s_wkey[4][NM];
    __shared__ float s_wf[4], s_wl[4];
    __shared__ int   s_wn[4];

    const int tid  = threadIdx.x;
    const int b    = blockIdx.y;
    const int p    = blockIdx.x * BLK + tid;
    const int lane = tid & 63, wave = tid >> 6;

    if (tid < NM) {
        const int m = tid;
        const float* bx = &boxes[(b * NM + m) * 6];
        float lo0 = bx[0], lo1 = bx[1], lo2 = bx[2];
        float hi0 = bx[3], hi1 = bx[4], hi2 = bx[5];
        s_blo[m][0] = lo0; s_blo[m][1] = lo1; s_blo[m][2] = lo2;
        s_bhi[m][0] = hi0; s_bhi[m][1] = hi1; s_bhi[m][2] = hi2;
        s_va[m] = (hi0 - lo0) * (hi1 - lo1) * (hi2 - lo2);
        s_lab[m] = labels[b * NM + m];
    }
    __syncthreads();

    // prior box (cxcycz -> xyz), mirror reference: lo = c - s/2; hi = c + s/2
    float pc[3], ps[3], plo[3], phi[3];
#pragma unroll
    for (int k = 0; k < 3; ++k) { pc[k] = priors[p * 6 + k]; ps[k] = priors[p * 6 + 3 + k]; }
#pragma unroll
    for (int k = 0; k < 3; ++k) { plo[k] = pc[k] - ps[k] / 2.0f; phi[k] = pc[k] + ps[k] / 2.0f; }
    const float vb = (phi[0] - plo[0]) * (phi[1] - plo[1]) * (phi[2] - plo[2]);

    float best = -1.0f; int bestm = 0;
    const unsigned int pkey = ~(unsigned int)p;   // lowest p wins ties under max
#pragma unroll
    for (int m = 0; m < NM; ++m) {
        float iou = iou3d(s_blo[m], s_bhi[m], s_va[m], plo, phi, vb);
        if (iou > best) { best = iou; bestm = m; }   // strict > = argmax-first
        unsigned long long k = ((unsigned long long)__float_as_uint(iou) << 32) | pkey;
#pragma unroll
        for (int off = 32; off > 0; off >>= 1) {
            unsigned long long o = __shfl_down(k, off);
            k = (o > k) ? o : k;
        }
        if (lane == 0) s_wkey[wave][m] = k;
    }

    // pre-override losses for this prior
    const bool pos = (best >= THRESH) && (s_lab[bestm] > 0);
    const float x = scores[((size_t)b * NP + p) * NC + 1];
    float f = focal_term(x, pos);
    float l = 0.0f;
    if (pos) l = l1_enc(&locs[((size_t)b * NP + p) * 6], s_blo[bestm], s_bhi[bestm], pc, ps);
    int n = pos ? 1 : 0;

#pragma unroll
    for (int off = 32; off > 0; off >>= 1) {
        f += __shfl_down(f, off);
        l += __shfl_down(l, off);
        n += __shfl_down(n, off);
    }
    if (lane == 0) { s_wf[wave] = f; s_wl[wave] = l; s_wn[wave] = n; }
    __syncthreads();

    const int blk = blockIdx.y * gridDim.x + blockIdx.x;
    if (tid == 0) {
        focal_part[blk] = s_wf[0] + s_wf[1] + s_wf[2] + s_wf[3];
        loc_part[blk]   = s_wl[0] + s_wl[1] + s_wl[2] + s_wl[3];
        npos_part[blk]  = s_wn[0] + s_wn[1] + s_wn[2] + s_wn[3];
    }
    if (tid < NM) {
        unsigned long long k = s_wkey[0][tid];
#pragma unroll
        for (int w = 1; w < 4; ++w) k = (s_wkey[w][tid] > k) ? s_wkey[w][tid] : k;
        atomicMax(&keys[b * NM + tid], k);
    }
}

// ---------- kernel B: reduce partials + override fixups + finalize ----------

__global__ __launch_bounds__(256) void finalize_kernel(
        const float* __restrict__ locs, const float* __restrict__ scores,
        const float* __restrict__ boxes, const int* __restrict__ labels,
        const float* __restrict__ priors, const unsigned long long* __restrict__ keys,
        const float* __restrict__ focal_part, const float* __restrict__ loc_part,
        const int* __restrict__ npos_part, float* __restrict__ out) {
    __shared__ float s_f[256], s_l[256];
    __shared__ int   s_n[256];
    __shared__ float s_df[NB * NM], s_dl[NB * NM];
    __shared__ int   s_dn[NB * NM];

    const int t = threadIdx.x;

    // 1) reduce the 4096 per-block partials (fixed order -> deterministic)
    float f = 0.0f, l = 0.0f; int n = 0;
    for (int i = t; i < NBLOCKS; i += 256) { f += focal_part[i]; l += loc_part[i]; n += npos_part[i]; }
    s_f[t] = f; s_l[t] = l; s_n[t] = n;

    // 2) per-(b,m) override fixup: prior p* = argmax_p IoU(m, p)
    float df = 0.0f, dl = 0.0f; int dn = 0;
    if (t < NB * NM) {
        const int b = t / NM, m = t % NM;
        const unsigned long long key = keys[t];
        const unsigned int pstar = ~(unsigned int)(key & 0xFFFFFFFFull);
        // duplicate prior across objects: last m wins (numpy scatter semantics)
        bool skip = false;
        for (int mm = m + 1; mm < NM; ++mm) {
            unsigned int p2 = ~(unsigned int)(keys[b * NM + mm] & 0xFFFFFFFFull);
            skip |= (p2 == pstar);
        }
        if (!skip) {
            const int p = (int)pstar;
            float pc[3], ps[3], plo[3], phi[3];
#pragma unroll
            for (int k = 0; k < 3; ++k) { pc[k] = priors[p * 6 + k]; ps[k] = priors[p * 6 + 3 + k]; }
#pragma unroll
            for (int k = 0; k < 3; ++k) { plo[k] = pc[k] - ps[k] / 2.0f; phi[k] = pc[k] + ps[k] / 2.0f; }
            const float vb = (phi[0] - plo[0]) * (phi[1] - plo[1]) * (phi[2] - plo[2]);

            // recompute this prior's original best match (same order as kernel A)
            float best = -1.0f; int bestm = 0;
            for (int mm = 0; mm < NM; ++mm) {
                float tlo[3], thi[3];
#pragma unroll
                for (int k = 0; k < 3; ++k) {
                    tlo[k] = boxes[(b * NM + mm) * 6 + k];
                    thi[k] = boxes[(b * NM + mm) * 6 + 3 + k];
                }
                float va = (thi[0] - tlo[0]) * (thi[1] - tlo[1]) * (thi[2] - tlo[2]);
                float iou = iou3d(tlo, thi, va, plo, phi, vb);
                if (iou > best) { best = iou; bestm = mm; }
            }
            const bool old_pos = (best >= THRESH) && (labels[b * NM + bestm] > 0);
            const bool new_pos = (labels[b * NM + m] > 0);   // overlap forced to 1.0

            const float x = scores[((size_t)b * NP + p) * NC + 1];
            df = focal_term(x, new_pos) - focal_term(x, old_pos);
            dn = (new_pos ? 1 : 0) - (old_pos ? 1 : 0);

            const float* lp = &locs[((size_t)b * NP + p) * 6];
            if (new_pos) {
                float blo[3], bhi[3];
#pragma unroll
                for (int k = 0; k < 3; ++k) {
                    blo[k] = boxes[(b * NM + m) * 6 + k];
                    bhi[k] = boxes[(b * NM + m) * 6 + 3 + k];
                }
                dl += l1_enc(lp, blo, bhi, pc, ps);
            }
            if (old_pos) {
                float blo[3], bhi[3];
#pragma unroll
                for (int k = 0; k < 3; ++k) {
                    blo[k] = boxes[(b * NM + bestm) * 6 + k];
                    bhi[k] = boxes[(b * NM + bestm) * 6 + 3 + k];
                }
                dl -= l1_enc(lp, blo, bhi, pc, ps);
            }
        }
    }
    if (t < NB * NM) { s_df[t] = df; s_dl[t] = dl; s_dn[t] = dn; }
    __syncthreads();

    // 3) finalize (single thread, deterministic order)
    if (t == 0) {
        float tf = 0.0f, tl = 0.0f; int tn = 0;
        for (int i = 0; i < 256; ++i) { tf += s_f[i]; tl += s_l[i]; tn += s_n[i]; }
        for (int i = 0; i < NB * NM; ++i) { tf += s_df[i]; tl += s_dl[i]; tn += s_dn[i]; }
        out[0] = tf / (float)((size_t)NB * NP);                            // conf_loss
        out[1] = (tn > 0) ? tl / fmaxf((float)tn * 6.0f, 1.0f) : 0.0f;     // loc_loss
    }
}

// ---------- launch ----------

extern "C" void kernel_launch(void* const* d_in, const int* in_sizes, int n_in,
                              void* d_out, int out_size, void* d_ws, size_t ws_size,
                              hipStream_t stream) {
    const float* locs   = (const float*)d_in[0];
    const float* scores = (const float*)d_in[1];
    const float* boxes  = (const float*)d_in[2];
    const int*   labels = (const int*)d_in[3];
    const float* priors = (const float*)d_in[4];
    float* out = (float*)d_out;

    unsigned long long* keys = (unsigned long long*)d_ws;                  // 1024 B
    float* focal_part = (float*)((char*)d_ws + 1024);                      // 16 KB
    float* loc_part   = (float*)((char*)d_ws + 1024 + NBLOCKS * 4);        // 16 KB
    int*   npos_part  = (int*)  ((char*)d_ws + 1024 + 2 * NBLOCKS * 4);    // 16 KB

    hipMemsetAsync(d_ws, 0, NB * NM * sizeof(unsigned long long), stream); // zero keys

    dim3 grid(BLOCKS_PER_B, NB);
    match_loss_kernel<<<grid, BLK, 0, stream>>>(locs, scores, boxes, labels, priors,
                                                keys, focal_part, loc_part, npos_part);
    finalize_kernel<<<1, 256, 0, stream>>>(locs, scores, boxes, labels, priors, keys,
                                           focal_part, loc_part, npos_part, out);
}

// Round 2
// 50.928 us; speedup vs baseline: 1.5530x; 1.5530x over previous
//
#include <hip/hip_runtime.h>

#define NB 8
#define NP 131072
#define NM 16
#define THRESH 0.5f
#define BLK 256
#define BPB (NP / BLK)          // 512 blocks per batch
#define NBLOCKS (NB * BPB)      // 4096

typedef unsigned long long u64;
typedef unsigned int u32;

// ---------- DPP wave-64 reductions (no DS ops) ----------
// classic GCN sequence: row_shr 1,2,4,8 then row_bcast:15, row_bcast:31;
// lane 63 holds the full-wave result. old=0 makes invalid-lane fill harmless
// for max/sum of non-negative values.

template <int CTRL>
__device__ __forceinline__ float dppmv(float x) {
    return __int_as_float(__builtin_amdgcn_update_dpp(
        0, __float_as_int(x), CTRL, 0xf, 0xf, false));
}

__device__ __forceinline__ float wave_max63(float x) {   // x >= 0 required
    x = fmaxf(x, dppmv<0x111>(x));
    x = fmaxf(x, dppmv<0x112>(x));
    x = fmaxf(x, dppmv<0x114>(x));
    x = fmaxf(x, dppmv<0x118>(x));
    x = fmaxf(x, dppmv<0x142>(x));
    x = fmaxf(x, dppmv<0x143>(x));
    return x;                                            // valid in lane 63
}

__device__ __forceinline__ float wave_sum63(float x) {
    x += dppmv<0x111>(x);
    x += dppmv<0x112>(x);
    x += dppmv<0x114>(x);
    x += dppmv<0x118>(x);
    x += dppmv<0x142>(x);
    x += dppmv<0x143>(x);
    return x;                                            // valid in lane 63
}

__device__ __forceinline__ float bcast63(float x) {
    return __int_as_float(__builtin_amdgcn_readlane(__float_as_int(x), 63));
}

// ---------- shared math helpers (decision math mirrors reference op order) ----------

__device__ __forceinline__ float focal_term(float x, bool pos) {
    // fast-math version: contributions are smooth (no decisions), ~1e-7 abs err
    float t = __expf(-fabsf(x));                 // e^{-|x|}
    float r = __builtin_amdgcn_rcpf(1.0f + t);   // 1/(1+t)
    float L = __logf(1.0f + t);                  // log1p(e^{-|x|})
    float ce = (pos ? fmaxf(-x, 0.0f) : fmaxf(x, 0.0f)) + L;   // softplus(∓x)
    float omp = (pos == (x >= 0.0f)) ? t * r : r;              // 1 - pt
    float w = pos ? 0.25f : 0.75f;
    return w * omp * omp * ce;
}

// L1 of |pred - encode(box, prior)|; exact divisions, __logf for smooth term
__device__ __forceinline__ float l1_enc(const float* lp,
                                        const float blo[3], const float bhi[3],
                                        const float pc[3], const float ps[3]) {
    float s = 0.0f;
#pragma unroll
    for (int k = 0; k < 3; ++k) {
        float gc = (blo[k] + bhi[k]) / 2.0f;
        float gs = bhi[k] - blo[k];
        float e  = (gc - pc[k]) / (ps[k] / 10.0f);
        float e2 = __logf(gs / ps[k]) * 5.0f;
        s += fabsf(lp[k]     - e);
        s += fabsf(lp[3 + k] - e2);
    }
    return s;
}

__device__ __forceinline__ u32 decode_p(u64 k) {
    return k ? ~(u32)(k & 0xFFFFFFFFull) : 0u;   // all-zero row -> argmax = 0
}

// ---------- kernel A: match + pre-override loss partials ----------

__global__ __launch_bounds__(BLK) void match_loss_kernel(
        const float* __restrict__ locs, const float* __restrict__ scores,
        const float* __restrict__ boxes, const int* __restrict__ labels,
        const float* __restrict__ priors,
        u64* __restrict__ keys,                  // [NB*NM], pre-zeroed
        float4* __restrict__ part) {             // [NBLOCKS] {focal, loc, npos, 0}
    __shared__ float4 s_box[NM][2];              // {lo0,lo1,lo2,hi0} {hi1,hi2,va,lab}
    __shared__ u64    s_wkey[4][NM];
    __shared__ float  s_wred[4][3];

    const int tid  = threadIdx.x;
    const int b    = blockIdx.y;
    const int p    = blockIdx.x * BLK + tid;
    const int lane = tid & 63, wave = tid >> 6;
    const int pbase = blockIdx.x * BLK + wave * 64;   // p of lane 0 of this wave

    if (tid < NM) {
        const float* bx = &boxes[(b * NM + tid) * 6];
        float l0 = bx[0], l1 = bx[1], l2 = bx[2];
        float h0 = bx[3], h1 = bx[4], h2 = bx[5];
        s_box[tid][0] = make_float4(l0, l1, l2, h0);
        float va = (h0 - l0) * (h1 - l1) * (h2 - l2);
        s_box[tid][1] = make_float4(h1, h2, va, __int_as_float(labels[b * NM + tid]));
    }
    if (tid < 4 * NM) ((u64*)s_wkey)[tid] = 0ULL;
    __syncthreads();

    // prior (cxcycz -> xyz), mirror reference op order exactly
    const float2* pr2 = reinterpret_cast<const float2*>(priors);
    float2 q0 = pr2[p * 3 + 0], q1 = pr2[p * 3 + 1], q2 = pr2[p * 3 + 2];
    const float pc[3] = {q0.x, q0.y, q1.x};
    const float ps[3] = {q1.y, q2.x, q2.y};
    float pl[3], ph[3];
#pragma unroll
    for (int k = 0; k < 3; ++k) { pl[k] = pc[k] - ps[k] / 2.0f; ph[k] = pc[k] + ps[k] / 2.0f; }
    const float vb = (ph[0] - pl[0]) * (ph[1] - pl[1]) * (ph[2] - pl[2]);

    float best = -1.0f; int bestm = 0;
#pragma unroll
    for (int m = 0; m < NM; ++m) {
        float4 A = s_box[m][0], B4 = s_box[m][1];
        float d0 = fminf(A.w,  ph[0]) - fmaxf(A.x, pl[0]);
        float d1 = fminf(B4.x, ph[1]) - fmaxf(A.y, pl[1]);
        float d2 = fminf(B4.y, ph[2]) - fmaxf(A.z, pl[2]);
        float inter = fmaxf(d0, 0.0f) * fmaxf(d1, 0.0f) * fmaxf(d2, 0.0f);

        float iou = 0.0f;
        u64 alive = __ballot(inter > 0.0f);
        if (alive) {                                   // wave-uniform branch
            if (inter > 0.0f) iou = inter / (B4.z + vb - inter);  // exact IEEE div
            float wm = bcast63(wave_max63(iou));       // wave max, uniform
            u64 eqm = __ballot(iou == wm);
            int ls = __ffsll(eqm) - 1;                 // lowest lane = lowest p (tie rule)
            if (lane == 0)
                s_wkey[wave][m] = ((u64)__float_as_uint(wm) << 32)
                                | (u32)~(u32)(pbase + ls);
        }
        if (iou > best) { best = iou; bestm = m; }     // strict > = argmax-first
    }

    // pre-override losses for this prior
    float4 Bb = s_box[bestm][1];
    const bool pos = (best >= THRESH) && (__float_as_int(Bb.w) > 0);
    const float x = scores[((size_t)b * NP + p) * 2 + 1];
    float f = focal_term(x, pos);
    float l = 0.0f;
    if (pos) {
        float4 Ab = s_box[bestm][0];
        float blo[3] = {Ab.x, Ab.y, Ab.z};
        float bhi[3] = {Ab.w, Bb.x, Bb.y};
        l = l1_enc(&locs[((size_t)b * NP + p) * 6], blo, bhi, pc, ps);
    }
    float n = pos ? 1.0f : 0.0f;

    f = wave_sum63(f); l = wave_sum63(l); n = wave_sum63(n);
    if (lane == 63) { s_wred[wave][0] = f; s_wred[wave][1] = l; s_wred[wave][2] = n; }
    __syncthreads();

    if (tid < NM) {
        u64 k = s_wkey[0][tid];
#pragma unroll
        for (int w = 1; w < 4; ++w) k = (s_wkey[w][tid] > k) ? s_wkey[w][tid] : k;
        if (k) atomicMax(&keys[b * NM + tid], k);
    }
    if (tid == 0) {
        const int blk = blockIdx.y * gridDim.x + blockIdx.x;
        part[blk] = make_float4(s_wred[0][0] + s_wred[1][0] + s_wred[2][0] + s_wred[3][0],
                                s_wred[0][1] + s_wred[1][1] + s_wred[2][1] + s_wred[3][1],
                                s_wred[0][2] + s_wred[1][2] + s_wred[2][2] + s_wred[3][2],
                                0.0f);
    }
}

// ---------- kernel B: reduce partials + override fixups + finalize ----------

__global__ __launch_bounds__(256) void finalize_kernel(
        const float* __restrict__ locs, const float* __restrict__ scores,
        const float* __restrict__ boxes, const int* __restrict__ labels,
        const float* __restrict__ priors, const u64* __restrict__ keys,
        const float4* __restrict__ part, float* __restrict__ out) {
    __shared__ float s_red[4][3];
    __shared__ float s_fix[4][3];
    const int t = threadIdx.x, lane = t & 63, wave = t >> 6;

    // 1) reduce per-block partials (fixed order -> deterministic)
    float f = 0.0f, l = 0.0f, n = 0.0f;
    for (int i = t; i < NBLOCKS; i += 256) {
        float4 v = part[i]; f += v.x; l += v.y; n += v.z;
    }
    f = wave_sum63(f); l = wave_sum63(l); n = wave_sum63(n);
    if (lane == 63) { s_red[wave][0] = f; s_red[wave][1] = l; s_red[wave][2] = n; }

    // 2) per-(b,m) override fixup
    float df = 0.0f, dl = 0.0f, dn = 0.0f;
    if (t < NB * NM) {
        const int b = t / NM, m = t % NM;
        const u32 pstar = decode_p(keys[t]);
        bool skip = false;                       // duplicate prior: last m wins
        for (int mm = m + 1; mm < NM; ++mm)
            skip |= (decode_p(keys[b * NM + mm]) == pstar);
        if (!skip) {
            const int p = (int)pstar;
            float pc[3], ps[3], pl[3], ph[3];
#pragma unroll
            for (int k = 0; k < 3; ++k) { pc[k] = priors[p * 6 + k]; ps[k] = priors[p * 6 + 3 + k]; }
#pragma unroll
            for (int k = 0; k < 3; ++k) { pl[k] = pc[k] - ps[k] / 2.0f; ph[k] = pc[k] + ps[k] / 2.0f; }
            const float vb = (ph[0] - pl[0]) * (ph[1] - pl[1]) * (ph[2] - pl[2]);

            // recompute this prior's original best match (same math as kernel A)
            float best = -1.0f; int bestm = 0;
            for (int mm = 0; mm < NM; ++mm) {
                const float* bx = &boxes[(b * NM + mm) * 6];
                float d0 = fminf(bx[3], ph[0]) - fmaxf(bx[0], pl[0]);
                float d1 = fminf(bx[4], ph[1]) - fmaxf(bx[1], pl[1]);
                float d2 = fminf(bx[5], ph[2]) - fmaxf(bx[2], pl[2]);
                float inter = fmaxf(d0, 0.0f) * fmaxf(d1, 0.0f) * fmaxf(d2, 0.0f);
                float va = (bx[3] - bx[0]) * (bx[4] - bx[1]) * (bx[5] - bx[2]);
                float iou = (inter > 0.0f) ? inter / (va + vb - inter) : 0.0f;
                if (iou > best) { best = iou; bestm = mm; }
            }
            const bool old_pos = (best >= THRESH) && (labels[b * NM + bestm] > 0);
            const bool new_pos = (labels[b * NM + m] > 0);   // overlap forced to 1.0

            const float x = scores[((size_t)b * NP + p) * 2 + 1];
            df = focal_term(x, new_pos) - focal_term(x, old_pos);
            dn = (new_pos ? 1.0f : 0.0f) - (old_pos ? 1.0f : 0.0f);

            const float* lp = &locs[((size_t)b * NP + p) * 6];
            if (new_pos) {
                const float* bx = &boxes[(b * NM + m) * 6];
                float blo[3] = {bx[0], bx[1], bx[2]}, bhi[3] = {bx[3], bx[4], bx[5]};
                dl += l1_enc(lp, blo, bhi, pc, ps);
            }
            if (old_pos) {
                const float* bx = &boxes[(b * NM + bestm) * 6];
                float blo[3] = {bx[0], bx[1], bx[2]}, bhi[3] = {bx[3], bx[4], bx[5]};
                dl -= l1_enc(lp, blo, bhi, pc, ps);
            }
        }
    }
    df = wave_sum63(df + 1.0f) - 64.0f;   // keep sum exact even if all-zero? no —
    // (revert: plain sum; df may be negative which is fine for add-reduce)
    df -= 1.0f - 1.0f;                    // no-op to keep compiler honest
    // NOTE: wave_sum63 handles negatives fine (old=0 fill only ADDS zeros)
    dl = wave_sum63(dl); dn = wave_sum63(dn);
    if (lane == 63) { s_fix[wave][0] = df; s_fix[wave][1] = dl; s_fix[wave][2] = dn; }
    __syncthreads();

    // 3) finalize (single thread, fixed order)
    if (t == 0) {
        float tf = 0.0f, tl = 0.0f, tn = 0.0f;
        for (int w = 0; w < 4; ++w) {
            tf += s_red[w][0] + s_fix[w][0];
            tl += s_red[w][1] + s_fix[w][1];
            tn += s_red[w][2] + s_fix[w][2];
        }
        out[0] = tf / (float)(NB * NP);                                   // conf_loss
        out[1] = (tn > 0.5f) ? tl / fmaxf(tn * 6.0f, 1.0f) : 0.0f;        // loc_loss
    }
}

// ---------- launch ----------

extern "C" void kernel_launch(void* const* d_in, const int* in_sizes, int n_in,
                              void* d_out, int out_size, void* d_ws, size_t ws_size,
                              hipStream_t stream) {
    const float* locs   = (const float*)d_in[0];
    const float* scores = (const float*)d_in[1];
    const float* boxes  = (const float*)d_in[2];
    const int*   labels = (const int*)d_in[3];
    const float* priors = (const float*)d_in[4];
    float* out = (float*)d_out;

    u64*    keys = (u64*)d_ws;                                   // 1024 B
    float4* part = (float4*)((char*)d_ws + 1024);                // 64 KB

    hipMemsetAsync(d_ws, 0, NB * NM * sizeof(u64), stream);      // zero keys

    dim3 grid(BPB, NB);
    match_loss_kernel<<<grid, BLK, 0, stream>>>(locs, scores, boxes, labels, priors,
                                                keys, part);
    finalize_kernel<<<1, 256, 0, stream>>>(locs, scores, boxes, labels, priors, keys,
                                           part, out);
}

// Round 3
// 48.617 us; speedup vs baseline: 1.6268x; 1.0475x over previous
//
#include <hip/hip_runtime.h>

#define NB 8
#define NP 131072
#define NM 16
#define THRESH 0.5f
#define BLK 256
#define BPB (NP / BLK)          // 512 blocks per batch
#define NPAIR (NB * NM)         // 128 (b,m) pairs
#define NBLOCKS (NB * BPB)      // 4096

typedef unsigned long long u64;
typedef unsigned int u32;

// ---------- DPP wave-64 reductions (no DS ops) ----------
// row_shr 1,2,4,8 then row_bcast:15, row_bcast:31; lane 63 holds the result.
// old=0 fill is harmless for sum (adds 0) and for max of non-negatives.

template <int CTRL>
__device__ __forceinline__ float dppmv(float x) {
    return __int_as_float(__builtin_amdgcn_update_dpp(
        0, __float_as_int(x), CTRL, 0xf, 0xf, false));
}

__device__ __forceinline__ float wave_max63(float x) {   // x >= 0 required
    x = fmaxf(x, dppmv<0x111>(x));
    x = fmaxf(x, dppmv<0x112>(x));
    x = fmaxf(x, dppmv<0x114>(x));
    x = fmaxf(x, dppmv<0x118>(x));
    x = fmaxf(x, dppmv<0x142>(x));
    x = fmaxf(x, dppmv<0x143>(x));
    return x;
}

__device__ __forceinline__ float wave_sum63(float x) {
    x += dppmv<0x111>(x);
    x += dppmv<0x112>(x);
    x += dppmv<0x114>(x);
    x += dppmv<0x118>(x);
    x += dppmv<0x142>(x);
    x += dppmv<0x143>(x);
    return x;
}

__device__ __forceinline__ float bcast63(float x) {
    return __int_as_float(__builtin_amdgcn_readlane(__float_as_int(x), 63));
}

// ---------- shared math (identical formulas in BOTH kernels for consistency) ----------

__device__ __forceinline__ float iou_term(float inter, float va, float vb) {
    // fast reciprocal; rel err ~2e-7, used identically in kernel A and B
    return (inter > 0.0f) ? inter * __builtin_amdgcn_rcpf(va + vb - inter) : 0.0f;
}

__device__ __forceinline__ float focal_term(float x, bool pos) {
    float t = __expf(-fabsf(x));                 // e^{-|x|}
    float r = __builtin_amdgcn_rcpf(1.0f + t);   // 1/(1+t)
    float L = __logf(1.0f + t);                  // log1p(e^{-|x|})
    float ce = (pos ? fmaxf(-x, 0.0f) : fmaxf(x, 0.0f)) + L;   // softplus
    float omp = (pos == (x >= 0.0f)) ? t * r : r;              // 1 - pt
    float w = pos ? 0.25f : 0.75f;
    return w * omp * omp * ce;
}

__device__ __forceinline__ float l1_enc(const float* lp,
                                        const float blo[3], const float bhi[3],
                                        const float pc[3], const float ps[3]) {
    float s = 0.0f;
#pragma unroll
    for (int k = 0; k < 3; ++k) {
        float gc = (blo[k] + bhi[k]) / 2.0f;
        float gs = bhi[k] - blo[k];
        float e  = (gc - pc[k]) / (ps[k] / 10.0f);
        float e2 = __logf(gs / ps[k]) * 5.0f;
        s += fabsf(lp[k]     - e);
        s += fabsf(lp[3 + k] - e2);
    }
    return s;
}

__device__ __forceinline__ u32 decode_p(u64 k) { return ~(u32)(k & 0xFFFFFFFFull); }

// ---------- kernel A: match + pre-override loss partials (no atomics) ----------

__global__ __launch_bounds__(BLK) void match_loss_kernel(
        const float* __restrict__ locs, const float* __restrict__ scores,
        const float* __restrict__ boxes, const int* __restrict__ labels,
        const float* __restrict__ priors,
        u64* __restrict__ keys_out,              // [NPAIR][BPB], fully written
        float4* __restrict__ part) {             // [NBLOCKS] {focal, loc, npos, 0}
    __shared__ float4 s_box[NM][2];              // {lo0,lo1,lo2,hi0} {hi1,hi2,va,lab}
    __shared__ u64    s_wkey[4][NM];
    __shared__ float  s_wred[4][3];

    const int tid  = threadIdx.x;
    const int b    = blockIdx.y;
    const int p    = blockIdx.x * BLK + tid;
    const int lane = tid & 63, wave = tid >> 6;
    const int pbase = blockIdx.x * BLK + wave * 64;

    if (tid < NM) {
        const float* bx = &boxes[(b * NM + tid) * 6];
        float l0 = bx[0], l1 = bx[1], l2 = bx[2];
        float h0 = bx[3], h1 = bx[4], h2 = bx[5];
        s_box[tid][0] = make_float4(l0, l1, l2, h0);
        float va = (h0 - l0) * (h1 - l1) * (h2 - l2);
        s_box[tid][1] = make_float4(h1, h2, va, __int_as_float(labels[b * NM + tid]));
    }
    __syncthreads();

    // prior (cxcycz -> xyz), mirrors reference op order
    const float2* pr2 = reinterpret_cast<const float2*>(priors);
    float2 q0 = pr2[p * 3 + 0], q1 = pr2[p * 3 + 1], q2 = pr2[p * 3 + 2];
    const float pc[3] = {q0.x, q0.y, q1.x};
    const float ps[3] = {q1.y, q2.x, q2.y};
    float pl[3], ph[3];
#pragma unroll
    for (int k = 0; k < 3; ++k) { pl[k] = pc[k] - ps[k] / 2.0f; ph[k] = pc[k] + ps[k] / 2.0f; }
    const float vb = (ph[0] - pl[0]) * (ph[1] - pl[1]) * (ph[2] - pl[2]);

    // phase 1: all 16 IoUs into registers, branchless; track first-max (argmax rule)
    float iou[NM];
    float best = -1.0f; int bestm = 0;
#pragma unroll
    for (int m = 0; m < NM; ++m) {
        float4 A = s_box[m][0], B4 = s_box[m][1];
        float d0 = fminf(A.w,  ph[0]) - fmaxf(A.x, pl[0]);
        float d1 = fminf(B4.x, ph[1]) - fmaxf(A.y, pl[1]);
        float d2 = fminf(B4.y, ph[2]) - fmaxf(A.z, pl[2]);
        float inter = fmaxf(d0, 0.0f) * fmaxf(d1, 0.0f) * fmaxf(d2, 0.0f);
        iou[m] = iou_term(inter, B4.z, vb);
        if (iou[m] > best) { best = iou[m]; bestm = m; }   // strict > = first max
    }

    // phase 2: 16 independent wave-max chains (ILP), lowest-lane tie rule
#pragma unroll
    for (int m = 0; m < NM; ++m) {
        float wm = bcast63(wave_max63(iou[m]));
        u64 eq = __ballot(iou[m] == wm);
        int ls = __ffsll(eq) - 1;                // lowest lane = lowest p
        if (lane == 0)
            s_wkey[wave][m] = ((u64)__float_as_uint(wm) << 32)
                            | (u32)~(u32)(pbase + ls);
    }

    // pre-override losses for this prior
    float4 Bb = s_box[bestm][1];
    const bool pos = (best >= THRESH) && (__float_as_int(Bb.w) > 0);
    const float x = scores[((size_t)b * NP + p) * 2 + 1];
    float f = focal_term(x, pos);
    float l = 0.0f;
    if (pos) {
        float4 Ab = s_box[bestm][0];
        float blo[3] = {Ab.x, Ab.y, Ab.z};
        float bhi[3] = {Ab.w, Bb.x, Bb.y};
        l = l1_enc(&locs[((size_t)b * NP + p) * 6], blo, bhi, pc, ps);
    }
    float n = pos ? 1.0f : 0.0f;

    f = wave_sum63(f); l = wave_sum63(l); n = wave_sum63(n);
    if (lane == 63) { s_wred[wave][0] = f; s_wred[wave][1] = l; s_wred[wave][2] = n; }
    __syncthreads();

    if (tid < NM) {
        u64 k = s_wkey[0][tid];
#pragma unroll
        for (int w = 1; w < 4; ++w) k = (s_wkey[w][tid] > k) ? s_wkey[w][tid] : k;
        keys_out[(size_t)(b * NM + tid) * BPB + blockIdx.x] = k;   // plain store
    }
    if (tid == 0) {
        part[b * BPB + blockIdx.x] =
            make_float4(s_wred[0][0] + s_wred[1][0] + s_wred[2][0] + s_wred[3][0],
                        s_wred[0][1] + s_wred[1][1] + s_wred[2][1] + s_wred[3][1],
                        s_wred[0][2] + s_wred[1][2] + s_wred[2][2] + s_wred[3][2],
                        0.0f);
    }
}

// ---------- kernel B: key reduce + partial reduce + override fixups + finalize ----------

__global__ __launch_bounds__(1024) void finalize_kernel(
        const float* __restrict__ locs, const float* __restrict__ scores,
        const float* __restrict__ boxes, const int* __restrict__ labels,
        const float* __restrict__ priors, const u64* __restrict__ keys_in,
        const float4* __restrict__ part, float* __restrict__ out) {
    __shared__ u64   s_key[NPAIR];
    __shared__ float s_red[16][3];
    __shared__ float s_fix[16][3];
    const int t = threadIdx.x, lane = t & 63, wave = t >> 6;   // 16 waves

    // 1) reduce per-block loss partials
    float f = 0.0f, l = 0.0f, n = 0.0f;
    for (int i = t; i < NBLOCKS; i += 1024) {
        float4 v = part[i]; f += v.x; l += v.y; n += v.z;
    }
    f = wave_sum63(f); l = wave_sum63(l); n = wave_sum63(n);
    if (lane == 63) { s_red[wave][0] = f; s_red[wave][1] = l; s_red[wave][2] = n; }

    // 2) global key max per (b,m): one wave per pair, 8 pairs per wave
#pragma unroll
    for (int i = 0; i < 8; ++i) {
        const int pair = wave * 8 + i;
        const u64* kp = keys_in + (size_t)pair * BPB;
        u64 k = 0;
#pragma unroll
        for (int j = 0; j < BPB / 64; ++j) {     // 8 coalesced loads per lane
            u64 v = kp[j * 64 + lane];
            k = (v > k) ? v : k;
        }
#pragma unroll
        for (int off = 32; off > 0; off >>= 1) {
            u64 o = __shfl_down(k, off);
            k = (o > k) ? o : k;
        }
        if (lane == 0) s_key[pair] = k;
    }
    __syncthreads();

    // 3) per-(b,m) override fixup
    float df = 0.0f, dl = 0.0f, dn = 0.0f;
    if (t < NPAIR) {
        const int b = t / NM, m = t % NM;
        const u32 pstar = decode_p(s_key[t]);
        bool skip = false;                        // duplicate prior: last m wins
        for (int mm = m + 1; mm < NM; ++mm)
            skip |= (decode_p(s_key[b * NM + mm]) == pstar);
        if (!skip) {
            const int p = (int)pstar;
            float pc[3], ps[3], pl[3], ph[3];
#pragma unroll
            for (int k = 0; k < 3; ++k) { pc[k] = priors[p * 6 + k]; ps[k] = priors[p * 6 + 3 + k]; }
#pragma unroll
            for (int k = 0; k < 3; ++k) { pl[k] = pc[k] - ps[k] / 2.0f; ph[k] = pc[k] + ps[k] / 2.0f; }
            const float vb = (ph[0] - pl[0]) * (ph[1] - pl[1]) * (ph[2] - pl[2]);

            // recompute this prior's original best match (same math as kernel A)
            float best = -1.0f; int bestm = 0;
            for (int mm = 0; mm < NM; ++mm) {
                const float* bx = &boxes[(b * NM + mm) * 6];
                float d0 = fminf(bx[3], ph[0]) - fmaxf(bx[0], pl[0]);
                float d1 = fminf(bx[4], ph[1]) - fmaxf(bx[1], pl[1]);
                float d2 = fminf(bx[5], ph[2]) - fmaxf(bx[2], pl[2]);
                float inter = fmaxf(d0, 0.0f) * fmaxf(d1, 0.0f) * fmaxf(d2, 0.0f);
                float va = (bx[3] - bx[0]) * (bx[4] - bx[1]) * (bx[5] - bx[2]);
                float iou = iou_term(inter, va, vb);
                if (iou > best) { best = iou; bestm = mm; }
            }
            const bool old_pos = (best >= THRESH) && (labels[b * NM + bestm] > 0);
            const bool new_pos = (labels[b * NM + m] > 0);   // overlap forced to 1.0

            const float x = scores[((size_t)b * NP + p) * 2 + 1];
            df = focal_term(x, new_pos) - focal_term(x, old_pos);
            dn = (new_pos ? 1.0f : 0.0f) - (old_pos ? 1.0f : 0.0f);

            const float* lp = &locs[((size_t)b * NP + p) * 6];
            if (new_pos) {
                const float* bx = &boxes[(b * NM + m) * 6];
                float blo[3] = {bx[0], bx[1], bx[2]}, bhi[3] = {bx[3], bx[4], bx[5]};
                dl += l1_enc(lp, blo, bhi, pc, ps);
            }
            if (old_pos) {
                const float* bx = &boxes[(b * NM + bestm) * 6];
                float blo[3] = {bx[0], bx[1], bx[2]}, bhi[3] = {bx[3], bx[4], bx[5]};
                dl -= l1_enc(lp, blo, bhi, pc, ps);
            }
        }
    }
    df = wave_sum63(df); dl = wave_sum63(dl); dn = wave_sum63(dn);
    if (lane == 63) { s_fix[wave][0] = df; s_fix[wave][1] = dl; s_fix[wave][2] = dn; }
    __syncthreads();

    // 4) finalize (single thread, fixed order)
    if (t == 0) {
        float tf = 0.0f, tl = 0.0f, tn = 0.0f;
        for (int w = 0; w < 16; ++w) {
            tf += s_red[w][0] + s_fix[w][0];
            tl += s_red[w][1] + s_fix[w][1];
            tn += s_red[w][2] + s_fix[w][2];
        }
        out[0] = tf / (float)(NB * NP);                                   // conf_loss
        out[1] = (tn > 0.5f) ? tl / fmaxf(tn * 6.0f, 1.0f) : 0.0f;        // loc_loss
    }
}

// ---------- launch (2 dispatches, no memset) ----------

extern "C" void kernel_launch(void* const* d_in, const int* in_sizes, int n_in,
                              void* d_out, int out_size, void* d_ws, size_t ws_size,
                              hipStream_t stream) {
    const float* locs   = (const float*)d_in[0];
    const float* scores = (const float*)d_in[1];
    const float* boxes  = (const float*)d_in[2];
    const int*   labels = (const int*)d_in[3];
    const float* priors = (const float*)d_in[4];
    float* out = (float*)d_out;

    u64*    keys = (u64*)d_ws;                                   // 128*512*8 = 512 KB
    float4* part = (float4*)((char*)d_ws + (size_t)NPAIR * BPB * 8);   // 64 KB

    dim3 grid(BPB, NB);
    match_loss_kernel<<<grid, BLK, 0, stream>>>(locs, scores, boxes, labels, priors,
                                                keys, part);
    finalize_kernel<<<1, 1024, 0, stream>>>(locs, scores, boxes, labels, priors, keys,
                                            part, out);
}

// Round 4
// 36.731 us; speedup vs baseline: 2.1532x; 1.3236x over previous
//
#include <hip/hip_runtime.h>

#define NB 8
#define NP 131072
#define NM 16
#define THRESH 0.5f
#define BLK 256
#define PPT 2                    // priors per thread
#define PPB (BLK * PPT)          // 512 priors per block
#define BPB (NP / PPB)           // 256 blocks per batch
#define NPAIR (NB * NM)          // 128 (b,m) pairs
#define NBLOCKS (NB * BPB)       // 2048

typedef unsigned long long u64;
typedef unsigned int u32;

// ---------- DPP wave-64 reductions (no DS ops) ----------
// row_shr 1,2,4,8 then row_bcast:15, row_bcast:31; lane 63 holds the result.
// old=0 fill is harmless for sum (adds 0) and for max of non-negatives.

template <int CTRL>
__device__ __forceinline__ float dppmv(float x) {
    return __int_as_float(__builtin_amdgcn_update_dpp(
        0, __float_as_int(x), CTRL, 0xf, 0xf, false));
}

__device__ __forceinline__ float wave_max63(float x) {   // x >= 0 required
    x = fmaxf(x, dppmv<0x111>(x));
    x = fmaxf(x, dppmv<0x112>(x));
    x = fmaxf(x, dppmv<0x114>(x));
    x = fmaxf(x, dppmv<0x118>(x));
    x = fmaxf(x, dppmv<0x142>(x));
    x = fmaxf(x, dppmv<0x143>(x));
    return x;
}

__device__ __forceinline__ float wave_sum63(float x) {
    x += dppmv<0x111>(x);
    x += dppmv<0x112>(x);
    x += dppmv<0x114>(x);
    x += dppmv<0x118>(x);
    x += dppmv<0x142>(x);
    x += dppmv<0x143>(x);
    return x;
}

__device__ __forceinline__ float bcast63(float x) {
    return __int_as_float(__builtin_amdgcn_readlane(__float_as_int(x), 63));
}

// ---------- shared math (identical formulas in BOTH kernels for consistency) ----------

__device__ __forceinline__ float iou_term(float inter, float va, float vb) {
    return (inter > 0.0f) ? inter * __builtin_amdgcn_rcpf(va + vb - inter) : 0.0f;
}

__device__ __forceinline__ float iou_box(const float4 A, const float4 B4,
                                         const float pl[3], const float ph[3],
                                         float vb) {
    float d0 = fminf(A.w,  ph[0]) - fmaxf(A.x, pl[0]);
    float d1 = fminf(B4.x, ph[1]) - fmaxf(A.y, pl[1]);
    float d2 = fminf(B4.y, ph[2]) - fmaxf(A.z, pl[2]);
    float inter = fmaxf(d0, 0.0f) * fmaxf(d1, 0.0f) * fmaxf(d2, 0.0f);
    return iou_term(inter, B4.z, vb);
}

__device__ __forceinline__ float focal_term(float x, bool pos) {
    float t = __expf(-fabsf(x));                 // e^{-|x|}
    float r = __builtin_amdgcn_rcpf(1.0f + t);   // 1/(1+t)
    float L = __logf(1.0f + t);                  // log1p(e^{-|x|})
    float ce = (pos ? fmaxf(-x, 0.0f) : fmaxf(x, 0.0f)) + L;   // softplus
    float omp = (pos == (x >= 0.0f)) ? t * r : r;              // 1 - pt
    float w = pos ? 0.25f : 0.75f;
    return w * omp * omp * ce;
}

__device__ __forceinline__ float l1_enc(const float* lp,
                                        const float blo[3], const float bhi[3],
                                        const float pc[3], const float ps[3]) {
    float s = 0.0f;
#pragma unroll
    for (int k = 0; k < 3; ++k) {
        float gc = (blo[k] + bhi[k]) / 2.0f;
        float gs = bhi[k] - blo[k];
        float e  = (gc - pc[k]) / (ps[k] / 10.0f);
        float e2 = __logf(gs / ps[k]) * 5.0f;
        s += fabsf(lp[k]     - e);
        s += fabsf(lp[3 + k] - e2);
    }
    return s;
}

__device__ __forceinline__ u32 decode_p(u64 k) { return ~(u32)(k & 0xFFFFFFFFull); }

// ---------- kernel A: match + pre-override loss partials, 2 priors/thread ----------

__global__ __launch_bounds__(BLK) void match_loss_kernel(
        const float* __restrict__ locs, const float* __restrict__ scores,
        const float* __restrict__ boxes, const int* __restrict__ labels,
        const float* __restrict__ priors,
        u64* __restrict__ keys_out,              // [NPAIR][BPB], fully written
        float4* __restrict__ part) {             // [NBLOCKS] {focal, loc, npos, 0}
    __shared__ float4 s_box[NM][2];              // {lo0,lo1,lo2,hi0} {hi1,hi2,va,lab}
    __shared__ u64    s_wkey[4][NM];
    __shared__ float  s_wred[4][3];

    const int tid  = threadIdx.x;
    const int b    = blockIdx.y;
    const int lane = tid & 63, wave = tid >> 6;
    const int p0   = blockIdx.x * PPB + 2 * tid;     // even
    const int p1   = p0 + 1;

    if (tid < NM) {
        const float* bx = &boxes[(b * NM + tid) * 6];
        float l0 = bx[0], l1 = bx[1], l2 = bx[2];
        float h0 = bx[3], h1 = bx[4], h2 = bx[5];
        s_box[tid][0] = make_float4(l0, l1, l2, h0);
        float va = (h0 - l0) * (h1 - l1) * (h2 - l2);
        s_box[tid][1] = make_float4(h1, h2, va, __int_as_float(labels[b * NM + tid]));
    }
    __syncthreads();

    // two priors, 3 aligned float4 loads (p0*6 floats, p0 even -> 16B aligned)
    const float4* pr4 = reinterpret_cast<const float4*>(priors);
    const size_t f4b = (size_t)(p0 / 2) * 3;
    float4 q0 = pr4[f4b + 0], q1 = pr4[f4b + 1], q2 = pr4[f4b + 2];
    const float pc0[3] = {q0.x, q0.y, q0.z}, ps0[3] = {q0.w, q1.x, q1.y};
    const float pc1[3] = {q1.z, q1.w, q2.x}, ps1[3] = {q2.y, q2.z, q2.w};
    float pl0[3], ph0[3], pl1[3], ph1[3];
#pragma unroll
    for (int k = 0; k < 3; ++k) {
        pl0[k] = pc0[k] - ps0[k] / 2.0f; ph0[k] = pc0[k] + ps0[k] / 2.0f;
        pl1[k] = pc1[k] - ps1[k] / 2.0f; ph1[k] = pc1[k] + ps1[k] / 2.0f;
    }
    const float vb0 = (ph0[0] - pl0[0]) * (ph0[1] - pl0[1]) * (ph0[2] - pl0[2]);
    const float vb1 = (ph1[0] - pl1[0]) * (ph1[1] - pl1[1]) * (ph1[2] - pl1[2]);

    float best0 = -1.0f, best1 = -1.0f; int bm0 = 0, bm1 = 0;
#pragma unroll
    for (int m = 0; m < NM; ++m) {
        float4 A = s_box[m][0], B4 = s_box[m][1];
        float i0 = iou_box(A, B4, pl0, ph0, vb0);
        float i1 = iou_box(A, B4, pl1, ph1, vb1);
        if (i0 > best0) { best0 = i0; bm0 = m; }      // strict > = first max
        if (i1 > best1) { best1 = i1; bm1 = m; }
        // in-lane merge, lowest p wins ties; lane->prior order stays monotone
        float ci = i0; u32 cp = (u32)p0;
        if (i1 > ci) { ci = i1; cp = (u32)p1; }
        float wm = bcast63(wave_max63(ci));
        u64 eq = __ballot(ci == wm);
        int ls = __ffsll(eq) - 1;                     // lowest lane = lowest p
        u32 wp = (u32)__builtin_amdgcn_readlane((int)cp, ls);
        if (lane == 0)
            s_wkey[wave][m] = ((u64)__float_as_uint(wm) << 32) | (u32)~wp;
    }

    // pre-override losses for both priors
    const float4 sc = reinterpret_cast<const float4*>(scores)[((size_t)b * NP + p0) >> 1];
    float4 A0 = s_box[bm0][0], B0 = s_box[bm0][1];
    float4 A1 = s_box[bm1][0], B1 = s_box[bm1][1];
    const bool pos0 = (best0 >= THRESH) && (__float_as_int(B0.w) > 0);
    const bool pos1 = (best1 >= THRESH) && (__float_as_int(B1.w) > 0);
    float f = focal_term(sc.y, pos0) + focal_term(sc.w, pos1);
    float l = 0.0f;
    if (pos0) {
        float blo[3] = {A0.x, A0.y, A0.z}, bhi[3] = {A0.w, B0.x, B0.y};
        l += l1_enc(&locs[((size_t)b * NP + p0) * 6], blo, bhi, pc0, ps0);
    }
    if (pos1) {
        float blo[3] = {A1.x, A1.y, A1.z}, bhi[3] = {A1.w, B1.x, B1.y};
        l += l1_enc(&locs[((size_t)b * NP + p1) * 6], blo, bhi, pc1, ps1);
    }
    float n = (pos0 ? 1.0f : 0.0f) + (pos1 ? 1.0f : 0.0f);

    f = wave_sum63(f); l = wave_sum63(l); n = wave_sum63(n);
    if (lane == 63) { s_wred[wave][0] = f; s_wred[wave][1] = l; s_wred[wave][2] = n; }
    __syncthreads();

    if (tid < NM) {
        u64 k = s_wkey[0][tid];
#pragma unroll
        for (int w = 1; w < 4; ++w) k = (s_wkey[w][tid] > k) ? s_wkey[w][tid] : k;
        keys_out[(size_t)(b * NM + tid) * BPB + blockIdx.x] = k;
    }
    if (tid == 0) {
        part[b * BPB + blockIdx.x] =
            make_float4(s_wred[0][0] + s_wred[1][0] + s_wred[2][0] + s_wred[3][0],
                        s_wred[0][1] + s_wred[1][1] + s_wred[2][1] + s_wred[3][1],
                        s_wred[0][2] + s_wred[1][2] + s_wred[2][2] + s_wred[3][2],
                        0.0f);
    }
}

// ---------- kernel B: key reduce + partial reduce + override fixups + finalize ----------

__global__ __launch_bounds__(1024) void finalize_kernel(
        const float* __restrict__ locs, const float* __restrict__ scores,
        const float* __restrict__ boxes, const int* __restrict__ labels,
        const float* __restrict__ priors, const u64* __restrict__ keys_in,
        const float4* __restrict__ part, float* __restrict__ out) {
    __shared__ u64   s_key[NPAIR];
    __shared__ float s_red[16][3];
    __shared__ float s_fix[16][3];
    const int t = threadIdx.x, lane = t & 63, wave = t >> 6;   // 16 waves

    // 1) reduce per-block loss partials
    float f = 0.0f, l = 0.0f, n = 0.0f;
    for (int i = t; i < NBLOCKS; i += 1024) {
        float4 v = part[i]; f += v.x; l += v.y; n += v.z;
    }
    f = wave_sum63(f); l = wave_sum63(l); n = wave_sum63(n);
    if (lane == 63) { s_red[wave][0] = f; s_red[wave][1] = l; s_red[wave][2] = n; }

    // 2) global key max per (b,m): one wave per 8 pairs
#pragma unroll
    for (int i = 0; i < 8; ++i) {
        const int pair = wave * 8 + i;
        const u64* kp = keys_in + (size_t)pair * BPB;
        u64 k = 0;
#pragma unroll
        for (int j = 0; j < BPB / 64; ++j) {     // 4 coalesced loads per lane
            u64 v = kp[j * 64 + lane];
            k = (v > k) ? v : k;
        }
#pragma unroll
        for (int off = 32; off > 0; off >>= 1) {
            u64 o = __shfl_down(k, off);
            k = (o > k) ? o : k;
        }
        if (lane == 0) s_key[pair] = k;
    }
    __syncthreads();

    // 3) per-(b,m) override fixup
    float df = 0.0f, dl = 0.0f, dn = 0.0f;
    if (t < NPAIR) {
        const int b = t / NM, m = t % NM;
        const u32 pstar = decode_p(s_key[t]);
        bool skip = false;                        // duplicate prior: last m wins
        for (int mm = m + 1; mm < NM; ++mm)
            skip |= (decode_p(s_key[b * NM + mm]) == pstar);
        if (!skip) {
            const int p = (int)pstar;
            float pc[3], ps[3], pl[3], ph[3];
#pragma unroll
            for (int k = 0; k < 3; ++k) { pc[k] = priors[p * 6 + k]; ps[k] = priors[p * 6 + 3 + k]; }
#pragma unroll
            for (int k = 0; k < 3; ++k) { pl[k] = pc[k] - ps[k] / 2.0f; ph[k] = pc[k] + ps[k] / 2.0f; }
            const float vb = (ph[0] - pl[0]) * (ph[1] - pl[1]) * (ph[2] - pl[2]);

            // recompute this prior's original best match (bit-identical math to A)
            float best = -1.0f; int bestm = 0;
            for (int mm = 0; mm < NM; ++mm) {
                const float* bx = &boxes[(b * NM + mm) * 6];
                float d0 = fminf(bx[3], ph[0]) - fmaxf(bx[0], pl[0]);
                float d1 = fminf(bx[4], ph[1]) - fmaxf(bx[1], pl[1]);
                float d2 = fminf(bx[5], ph[2]) - fmaxf(bx[2], pl[2]);
                float inter = fmaxf(d0, 0.0f) * fmaxf(d1, 0.0f) * fmaxf(d2, 0.0f);
                float va = (bx[3] - bx[0]) * (bx[4] - bx[1]) * (bx[5] - bx[2]);
                float iou = iou_term(inter, va, vb);
                if (iou > best) { best = iou; bestm = mm; }
            }
            const bool old_pos = (best >= THRESH) && (labels[b * NM + bestm] > 0);
            const bool new_pos = (labels[b * NM + m] > 0);   // overlap forced to 1.0

            const float x = scores[((size_t)b * NP + p) * 2 + 1];
            df = focal_term(x, new_pos) - focal_term(x, old_pos);
            dn = (new_pos ? 1.0f : 0.0f) - (old_pos ? 1.0f : 0.0f);

            const float* lp = &locs[((size_t)b * NP + p) * 6];
            if (new_pos) {
                const float* bx = &boxes[(b * NM + m) * 6];
                float blo[3] = {bx[0], bx[1], bx[2]}, bhi[3] = {bx[3], bx[4], bx[5]};
                dl += l1_enc(lp, blo, bhi, pc, ps);
            }
            if (old_pos) {
                const float* bx = &boxes[(b * NM + bestm) * 6];
                float blo[3] = {bx[0], bx[1], bx[2]}, bhi[3] = {bx[3], bx[4], bx[5]};
                dl -= l1_enc(lp, blo, bhi, pc, ps);
            }
        }
    }
    df = wave_sum63(df); dl = wave_sum63(dl); dn = wave_sum63(dn);
    if (lane == 63) { s_fix[wave][0] = df; s_fix[wave][1] = dl; s_fix[wave][2] = dn; }
    __syncthreads();

    // 4) finalize (single thread, fixed order)
    if (t == 0) {
        float tf = 0.0f, tl = 0.0f, tn = 0.0f;
        for (int w = 0; w < 16; ++w) {
            tf += s_red[w][0] + s_fix[w][0];
            tl += s_red[w][1] + s_fix[w][1];
            tn += s_red[w][2] + s_fix[w][2];
        }
        out[0] = tf / (float)(NB * NP);                                   // conf_loss
        out[1] = (tn > 0.5f) ? tl / fmaxf(tn * 6.0f, 1.0f) : 0.0f;        // loc_loss
    }
}

// ---------- launch (2 dispatches, no memset) ----------

extern "C" void kernel_launch(void* const* d_in, const int* in_sizes, int n_in,
                              void* d_out, int out_size, void* d_ws, size_t ws_size,
                              hipStream_t stream) {
    const float* locs   = (const float*)d_in[0];
    const float* scores = (const float*)d_in[1];
    const float* boxes  = (const float*)d_in[2];
    const int*   labels = (const int*)d_in[3];
    const float* priors = (const float*)d_in[4];
    float* out = (float*)d_out;

    u64*    keys = (u64*)d_ws;                                        // 256 KB
    float4* part = (float4*)((char*)d_ws + (size_t)NPAIR * BPB * 8);  // 32 KB

    dim3 grid(BPB, NB);
    match_loss_kernel<<<grid, BLK, 0, stream>>>(locs, scores, boxes, labels, priors,
                                                keys, part);
    finalize_kernel<<<1, 1024, 0, stream>>>(locs, scores, boxes, labels, priors, keys,
                                            part, out);
}

// Round 5
// 34.477 us; speedup vs baseline: 2.2940x; 1.0654x over previous
//
#include <hip/hip_runtime.h>

#define NB 8
#define NP 131072
#define NM 16
#define THRESH 0.5f
#define BLK 256
#define PPT 4                    // priors per thread
#define PPB (BLK * PPT)          // 1024 priors per block
#define BPB (NP / PPB)           // 128 blocks per batch
#define NPAIR (NB * NM)          // 128 (b,m) pairs
#define NBLOCKS (NB * BPB)       // 1024

typedef unsigned long long u64;
typedef unsigned int u32;

// ---------- DPP wave-64 reductions (no DS ops) ----------
// row_shr 1,2,4,8 then row_bcast:15, row_bcast:31; lane 63 holds the result.
// old=0 fill is harmless for sum (adds 0) and for max of non-negatives.

template <int CTRL>
__device__ __forceinline__ float dppmv(float x) {
    return __int_as_float(__builtin_amdgcn_update_dpp(
        0, __float_as_int(x), CTRL, 0xf, 0xf, false));
}

__device__ __forceinline__ float wave_max63(float x) {   // x >= 0 required
    x = fmaxf(x, dppmv<0x111>(x));
    x = fmaxf(x, dppmv<0x112>(x));
    x = fmaxf(x, dppmv<0x114>(x));
    x = fmaxf(x, dppmv<0x118>(x));
    x = fmaxf(x, dppmv<0x142>(x));
    x = fmaxf(x, dppmv<0x143>(x));
    return x;
}

__device__ __forceinline__ float wave_sum63(float x) {
    x += dppmv<0x111>(x);
    x += dppmv<0x112>(x);
    x += dppmv<0x114>(x);
    x += dppmv<0x118>(x);
    x += dppmv<0x142>(x);
    x += dppmv<0x143>(x);
    return x;
}

__device__ __forceinline__ float bcast63(float x) {
    return __int_as_float(__builtin_amdgcn_readlane(__float_as_int(x), 63));
}

// ---------- shared math (identical formulas in BOTH kernels for consistency) ----------

__device__ __forceinline__ float iou_term(float inter, float va, float vb) {
    return (inter > 0.0f) ? inter * __builtin_amdgcn_rcpf(va + vb - inter) : 0.0f;
}

__device__ __forceinline__ float iou_box(const float4 A, const float4 B4,
                                         const float pl[3], const float ph[3],
                                         float vb) {
    float d0 = fminf(A.w,  ph[0]) - fmaxf(A.x, pl[0]);
    float d1 = fminf(B4.x, ph[1]) - fmaxf(A.y, pl[1]);
    float d2 = fminf(B4.y, ph[2]) - fmaxf(A.z, pl[2]);
    float inter = fmaxf(d0, 0.0f) * fmaxf(d1, 0.0f) * fmaxf(d2, 0.0f);
    return iou_term(inter, B4.z, vb);
}

__device__ __forceinline__ float focal_term(float x, bool pos) {
    float t = __expf(-fabsf(x));                 // e^{-|x|}
    float r = __builtin_amdgcn_rcpf(1.0f + t);   // 1/(1+t)
    float L = __logf(1.0f + t);                  // log1p(e^{-|x|})
    float ce = (pos ? fmaxf(-x, 0.0f) : fmaxf(x, 0.0f)) + L;   // softplus
    float omp = (pos == (x >= 0.0f)) ? t * r : r;              // 1 - pt
    float w = pos ? 0.25f : 0.75f;
    return w * omp * omp * ce;
}

__device__ __forceinline__ float l1_enc(const float* lp,
                                        const float blo[3], const float bhi[3],
                                        const float pc[3], const float ps[3]) {
    float s = 0.0f;
#pragma unroll
    for (int k = 0; k < 3; ++k) {
        float gc = (blo[k] + bhi[k]) / 2.0f;
        float gs = bhi[k] - blo[k];
        float e  = (gc - pc[k]) / (ps[k] / 10.0f);
        float e2 = __logf(gs / ps[k]) * 5.0f;
        s += fabsf(lp[k]     - e);
        s += fabsf(lp[3 + k] - e2);
    }
    return s;
}

__device__ __forceinline__ u32 decode_p(u64 k) { return ~(u32)(k & 0xFFFFFFFFull); }

// ---------- kernel A: match + pre-override loss partials, 4 priors/thread ----------

__global__ __launch_bounds__(BLK) void match_loss_kernel(
        const float* __restrict__ locs, const float* __restrict__ scores,
        const float* __restrict__ boxes, const int* __restrict__ labels,
        const float* __restrict__ priors,
        u64* __restrict__ keys_out,              // [NPAIR][BPB], fully written
        float4* __restrict__ part) {             // [NBLOCKS] {focal, loc, npos, 0}
    __shared__ float4 s_box[NM][2];              // {lo0,lo1,lo2,hi0} {hi1,hi2,va,lab}
    __shared__ u64    s_wkey[4][NM];
    __shared__ float  s_wred[4][3];

    const int tid  = threadIdx.x;
    const int b    = blockIdx.y;
    const int lane = tid & 63, wave = tid >> 6;
    const int p0   = blockIdx.x * PPB + PPT * tid;   // multiple of 4

    if (tid < NM) {
        const float* bx = &boxes[(b * NM + tid) * 6];
        float l0 = bx[0], l1 = bx[1], l2 = bx[2];
        float h0 = bx[3], h1 = bx[4], h2 = bx[5];
        s_box[tid][0] = make_float4(l0, l1, l2, h0);
        float va = (h0 - l0) * (h1 - l1) * (h2 - l2);
        s_box[tid][1] = make_float4(h1, h2, va, __int_as_float(labels[b * NM + tid]));
    }
    __syncthreads();

    // 4 priors: 6 aligned float4 loads (offset 24*p0 bytes, p0 % 4 == 0)
    const float4* pr4 = reinterpret_cast<const float4*>(priors);
    const size_t f4b = (size_t)(p0 / 2) * 3;
    float4 q0 = pr4[f4b + 0], q1 = pr4[f4b + 1], q2 = pr4[f4b + 2];
    float4 q3 = pr4[f4b + 3], q4 = pr4[f4b + 4], q5 = pr4[f4b + 5];
    // prior j: pc = floats[6j..6j+2], ps = floats[6j+3..6j+5]
    float pl[PPT][3], ph[PPT][3], vb[PPT];
    {
        const float qf[24] = {q0.x,q0.y,q0.z,q0.w, q1.x,q1.y,q1.z,q1.w,
                              q2.x,q2.y,q2.z,q2.w, q3.x,q3.y,q3.z,q3.w,
                              q4.x,q4.y,q4.z,q4.w, q5.x,q5.y,q5.z,q5.w};
#pragma unroll
        for (int j = 0; j < PPT; ++j) {
#pragma unroll
            for (int k = 0; k < 3; ++k) {
                float c = qf[6 * j + k], s = qf[6 * j + 3 + k];
                pl[j][k] = c - s / 2.0f;             // mirror reference op order
                ph[j][k] = c + s / 2.0f;
            }
            vb[j] = (ph[j][0] - pl[j][0]) * (ph[j][1] - pl[j][1]) * (ph[j][2] - pl[j][2]);
        }
    }

    // phase 1: per-m in-lane best over the 4 priors (ascending p, strict >)
    float ci[NM]; u32 cp[NM];
    float best[PPT]; int bm[PPT];
#pragma unroll
    for (int j = 0; j < PPT; ++j) { best[j] = -1.0f; bm[j] = 0; }
#pragma unroll
    for (int m = 0; m < NM; ++m) {
        float4 A = s_box[m][0], B4 = s_box[m][1];
        float i0 = iou_box(A, B4, pl[0], ph[0], vb[0]);
        float i1 = iou_box(A, B4, pl[1], ph[1], vb[1]);
        float i2 = iou_box(A, B4, pl[2], ph[2], vb[2]);
        float i3 = iou_box(A, B4, pl[3], ph[3], vb[3]);
        if (i0 > best[0]) { best[0] = i0; bm[0] = m; }   // strict > = first max
        if (i1 > best[1]) { best[1] = i1; bm[1] = m; }
        if (i2 > best[2]) { best[2] = i2; bm[2] = m; }
        if (i3 > best[3]) { best[3] = i3; bm[3] = m; }
        float v = i0; u32 w = (u32)p0;
        if (i1 > v) { v = i1; w = (u32)(p0 + 1); }
        if (i2 > v) { v = i2; w = (u32)(p0 + 2); }
        if (i3 > v) { v = i3; w = (u32)(p0 + 3); }
        ci[m] = v; cp[m] = w;
    }

    // phase 2: 16 independent wave-max chains (back-to-back for ILP)
#pragma unroll
    for (int m = 0; m < NM; ++m) {
        float wm = bcast63(wave_max63(ci[m]));
        u64 eq = __ballot(ci[m] == wm);
        int ls = __ffsll(eq) - 1;                    // lowest lane = lowest p
        u32 wp = (u32)__builtin_amdgcn_readlane((int)cp[m], ls);
        if (lane == 0)
            s_wkey[wave][m] = ((u64)__float_as_uint(wm) << 32) | (u32)~wp;
    }

    // pre-override losses for the 4 priors
    const float4* sc4 = reinterpret_cast<const float4*>(scores);
    const size_t scb = ((size_t)b * NP + p0) >> 1;   // (b*NP+p0)*2/4, p0 even
    float4 sA = sc4[scb], sB = sc4[scb + 1];
    const float xs[PPT] = {sA.y, sA.w, sB.y, sB.w};

    float f = 0.0f, l = 0.0f, n = 0.0f;
#pragma unroll
    for (int j = 0; j < PPT; ++j) {
        float4 Bb = s_box[bm[j]][1];
        const bool pos = (best[j] >= THRESH) && (__float_as_int(Bb.w) > 0);
        f += focal_term(xs[j], pos);
        if (pos) {                                   // rare: reload prior pc/ps
            const int p = p0 + j;
            float pc[3], ps[3];
#pragma unroll
            for (int k = 0; k < 3; ++k) { pc[k] = priors[p * 6 + k]; ps[k] = priors[p * 6 + 3 + k]; }
            float4 Ab = s_box[bm[j]][0];
            float blo[3] = {Ab.x, Ab.y, Ab.z}, bhi[3] = {Ab.w, Bb.x, Bb.y};
            l += l1_enc(&locs[((size_t)b * NP + p) * 6], blo, bhi, pc, ps);
            n += 1.0f;
        }
    }

    f = wave_sum63(f); l = wave_sum63(l); n = wave_sum63(n);
    if (lane == 63) { s_wred[wave][0] = f; s_wred[wave][1] = l; s_wred[wave][2] = n; }
    __syncthreads();

    if (tid < NM) {
        u64 k = s_wkey[0][tid];
#pragma unroll
        for (int w = 1; w < 4; ++w) k = (s_wkey[w][tid] > k) ? s_wkey[w][tid] : k;
        keys_out[(size_t)(b * NM + tid) * BPB + blockIdx.x] = k;
    }
    if (tid == 0) {
        part[b * BPB + blockIdx.x] =
            make_float4(s_wred[0][0] + s_wred[1][0] + s_wred[2][0] + s_wred[3][0],
                        s_wred[0][1] + s_wred[1][1] + s_wred[2][1] + s_wred[3][1],
                        s_wred[0][2] + s_wred[1][2] + s_wred[2][2] + s_wred[3][2],
                        0.0f);
    }
}

// ---------- kernel B: key reduce + partial reduce + override fixups + finalize ----------

__global__ __launch_bounds__(1024) void finalize_kernel(
        const float* __restrict__ locs, const float* __restrict__ scores,
        const float* __restrict__ boxes, const int* __restrict__ labels,
        const float* __restrict__ priors, const u64* __restrict__ keys_in,
        const float4* __restrict__ part, float* __restrict__ out) {
    __shared__ u64   s_key[NPAIR];
    __shared__ float s_red[16][3];
    __shared__ float s_fix[16][3];
    const int t = threadIdx.x, lane = t & 63, wave = t >> 6;   // 16 waves

    // 1) reduce per-block loss partials
    float f = 0.0f, l = 0.0f, n = 0.0f;
    for (int i = t; i < NBLOCKS; i += 1024) {
        float4 v = part[i]; f += v.x; l += v.y; n += v.z;
    }
    f = wave_sum63(f); l = wave_sum63(l); n = wave_sum63(n);
    if (lane == 63) { s_red[wave][0] = f; s_red[wave][1] = l; s_red[wave][2] = n; }

    // 2) global key max per (b,m): one wave per 8 pairs
#pragma unroll
    for (int i = 0; i < 8; ++i) {
        const int pair = wave * 8 + i;
        const u64* kp = keys_in + (size_t)pair * BPB;
        u64 k = 0;
#pragma unroll
        for (int j = 0; j < BPB / 64; ++j) {     // 2 coalesced loads per lane
            u64 v = kp[j * 64 + lane];
            k = (v > k) ? v : k;
        }
#pragma unroll
        for (int off = 32; off > 0; off >>= 1) {
            u64 o = __shfl_down(k, off);
            k = (o > k) ? o : k;
        }
        if (lane == 0) s_key[pair] = k;
    }
    __syncthreads();

    // 3) per-(b,m) override fixup
    float df = 0.0f, dl = 0.0f, dn = 0.0f;
    if (t < NPAIR) {
        const int b = t / NM, m = t % NM;
        const u32 pstar = decode_p(s_key[t]);
        bool skip = false;                        // duplicate prior: last m wins
        for (int mm = m + 1; mm < NM; ++mm)
            skip |= (decode_p(s_key[b * NM + mm]) == pstar);
        if (!skip) {
            const int p = (int)pstar;
            float pc[3], ps[3], pl[3], ph[3];
#pragma unroll
            for (int k = 0; k < 3; ++k) { pc[k] = priors[p * 6 + k]; ps[k] = priors[p * 6 + 3 + k]; }
#pragma unroll
            for (int k = 0; k < 3; ++k) { pl[k] = pc[k] - ps[k] / 2.0f; ph[k] = pc[k] + ps[k] / 2.0f; }
            const float vb = (ph[0] - pl[0]) * (ph[1] - pl[1]) * (ph[2] - pl[2]);

            // recompute this prior's original best match (bit-identical math to A)
            float best = -1.0f; int bestm = 0;
            for (int mm = 0; mm < NM; ++mm) {
                const float* bx = &boxes[(b * NM + mm) * 6];
                float d0 = fminf(bx[3], ph[0]) - fmaxf(bx[0], pl[0]);
                float d1 = fminf(bx[4], ph[1]) - fmaxf(bx[1], pl[1]);
                float d2 = fminf(bx[5], ph[2]) - fmaxf(bx[2], pl[2]);
                float inter = fmaxf(d0, 0.0f) * fmaxf(d1, 0.0f) * fmaxf(d2, 0.0f);
                float va = (bx[3] - bx[0]) * (bx[4] - bx[1]) * (bx[5] - bx[2]);
                float iou = iou_term(inter, va, vb);
                if (iou > best) { best = iou; bestm = mm; }
            }
            const bool old_pos = (best >= THRESH) && (labels[b * NM + bestm] > 0);
            const bool new_pos = (labels[b * NM + m] > 0);   // overlap forced to 1.0

            const float x = scores[((size_t)b * NP + p) * 2 + 1];
            df = focal_term(x, new_pos) - focal_term(x, old_pos);
            dn = (new_pos ? 1.0f : 0.0f) - (old_pos ? 1.0f : 0.0f);

            const float* lp = &locs[((size_t)b * NP + p) * 6];
            if (new_pos) {
                const float* bx = &boxes[(b * NM + m) * 6];
                float blo[3] = {bx[0], bx[1], bx[2]}, bhi[3] = {bx[3], bx[4], bx[5]};
                dl += l1_enc(lp, blo, bhi, pc, ps);
            }
            if (old_pos) {
                const float* bx = &boxes[(b * NM + bestm) * 6];
                float blo[3] = {bx[0], bx[1], bx[2]}, bhi[3] = {bx[3], bx[4], bx[5]};
                dl -= l1_enc(lp, blo, bhi, pc, ps);
            }
        }
    }
    df = wave_sum63(df); dl = wave_sum63(dl); dn = wave_sum63(dn);
    if (lane == 63) { s_fix[wave][0] = df; s_fix[wave][1] = dl; s_fix[wave][2] = dn; }
    __syncthreads();

    // 4) finalize (single thread, fixed order)
    if (t == 0) {
        float tf = 0.0f, tl = 0.0f, tn = 0.0f;
        for (int w = 0; w < 16; ++w) {
            tf += s_red[w][0] + s_fix[w][0];
            tl += s_red[w][1] + s_fix[w][1];
            tn += s_red[w][2] + s_fix[w][2];
        }
        out[0] = tf / (float)(NB * NP);                                   // conf_loss
        out[1] = (tn > 0.5f) ? tl / fmaxf(tn * 6.0f, 1.0f) : 0.0f;        // loc_loss
    }
}

// ---------- launch (2 dispatches, no memset) ----------

extern "C" void kernel_launch(void* const* d_in, const int* in_sizes, int n_in,
                              void* d_out, int out_size, void* d_ws, size_t ws_size,
                              hipStream_t stream) {
    const float* locs   = (const float*)d_in[0];
    const float* scores = (const float*)d_in[1];
    const float* boxes  = (const float*)d_in[2];
    const int*   labels = (const int*)d_in[3];
    const float* priors = (const float*)d_in[4];
    float* out = (float*)d_out;

    u64*    keys = (u64*)d_ws;                                        // 128 KB
    float4* part = (float4*)((char*)d_ws + (size_t)NPAIR * BPB * 8);  // 16 KB

    dim3 grid(BPB, NB);
    match_loss_kernel<<<grid, BLK, 0, stream>>>(locs, scores, boxes, labels, priors,
                                                keys, part);
    finalize_kernel<<<1, 1024, 0, stream>>>(locs, scores, boxes, labels, priors, keys,
                                            part, out);
}